// Round 3
// baseline (1222.628 us; speedup 1.0000x reference)
//
#include <hip/hip_runtime.h>
#include <hip/hip_bf16.h>
#include <hip/hip_fp16.h>

// SimpleRNN: B=64, S=2048, IN=256, H=128, OUT=3 (all fp32)
// Phase 1 (r12): xproj MFMA GEMM, now 2-phase reg-staged pipeline with
//   LDS-only barriers (global loads stay in flight across barriers).
// Phase 2 (r12): 1 wave/batch, zero barriers. r11's VGPR=92 proved the
//   128 weight half2s spilled to scratch (launch_bounds(64) let the
//   allocator target occupancy we don't need). Fix: launch_bounds(64,1)
//   + 128 individually NAMED weight registers via X-macros. Also drop the
//   post-write lgkmcnt (same-wave DS ops are processed in order).

#define RNN_B   64
#define RNN_S   2048
#define RNN_IN  256
#define RNN_H   128
#define RNN_OUT 3

typedef _Float16 half2v __attribute__((ext_vector_type(2)));
typedef _Float16 half4 __attribute__((ext_vector_type(4)));
typedef _Float16 half8 __attribute__((ext_vector_type(8)));
typedef float f32x4 __attribute__((ext_vector_type(4)));

#if __has_builtin(__builtin_amdgcn_fdot2)
#define FDOT2(a, b, c) __builtin_amdgcn_fdot2((a), (b), (c), false)
#else
#define FDOT2(a, b, c) \
  fmaf((float)(a).x, (float)(b).x, fmaf((float)(a).y, (float)(b).y, (c)))
#endif

// LDS-only barrier: drains lgkm (LDS) but NOT vmcnt, so global prefetch
// loads stay in flight across the barrier.
__device__ __forceinline__ void block_sync_lds() {
  asm volatile("s_waitcnt lgkmcnt(0)" ::: "memory");
  __builtin_amdgcn_s_barrier();
}

// ---------------------------------------------------------------------------
// Phase 1: f16 MFMA GEMM  C[M=131072, N=128] = A[M,256] * B[128,256]^T + bias
// 128x128 tile/block, 4 waves (2x2 of 64x64), mfma_f32_16x16x32_f16.
// 2-phase pipeline: regs stage chunk k+1 while LDS holds chunk k.
// ---------------------------------------------------------------------------
#define XLOADC(SET, KC)                                                       \
  {                                                                           \
    const int _kc = (KC);                                                     \
    _Pragma("unroll")                                                         \
    for (int p = 0; p < 4; ++p) {                                             \
      const int row = lr + 32 * p;                                            \
      SET##a[p] = *(const float4*)&x[(size_t)(m0 + row) * RNN_IN + _kc + lc]; \
      SET##b[p] = *(const float4*)&Wxh[(size_t)row * RNN_IN + _kc + lc];      \
    }                                                                         \
  }

#define XSTORE(SET)                                                 \
  {                                                                 \
    _Pragma("unroll")                                               \
    for (int p = 0; p < 4; ++p) {                                   \
      const int row = lr + 32 * p;                                  \
      half4 ha, hb;                                                 \
      ha.x = (_Float16)SET##a[p].x; ha.y = (_Float16)SET##a[p].y;   \
      ha.z = (_Float16)SET##a[p].z; ha.w = (_Float16)SET##a[p].w;   \
      hb.x = (_Float16)SET##b[p].x; hb.y = (_Float16)SET##b[p].y;   \
      hb.z = (_Float16)SET##b[p].z; hb.w = (_Float16)SET##b[p].w;   \
      *(half4*)&Ash[row][lc] = ha;                                  \
      *(half4*)&Bsh[row][lc] = hb;                                  \
    }                                                               \
  }

#define XCOMPUTE()                                                  \
  {                                                                 \
    half8 af[4], bf[4];                                             \
    _Pragma("unroll")                                               \
    for (int m = 0; m < 4; ++m)                                     \
      af[m] = *(const half8*)&Ash[wr * 64 + m * 16 + fr][fk * 8];   \
    _Pragma("unroll")                                               \
    for (int n = 0; n < 4; ++n)                                     \
      bf[n] = *(const half8*)&Bsh[wc * 64 + n * 16 + fr][fk * 8];   \
    _Pragma("unroll")                                               \
    for (int m = 0; m < 4; ++m)                                     \
      _Pragma("unroll")                                             \
      for (int n = 0; n < 4; ++n)                                   \
        acc[m][n] = __builtin_amdgcn_mfma_f32_16x16x32_f16(         \
            af[m], bf[n], acc[m][n], 0, 0, 0);                      \
  }

__global__ __launch_bounds__(256, 2) void xproj_mfma(
    const float* __restrict__ x, const float* __restrict__ Wxh,
    const float* __restrict__ bxh, float* __restrict__ xp) {
  __shared__ __align__(16) _Float16 Ash[128][40];
  __shared__ __align__(16) _Float16 Bsh[128][40];

  const int tid = threadIdx.x;
  const int m0 = blockIdx.x * 128;
  const int wv = tid >> 6;
  const int lane = tid & 63;
  const int wr = wv >> 1;          // wave row (0..1) -> M offset 64*wr
  const int wc = wv & 1;           // wave col (0..1) -> N offset 64*wc
  const int fr = lane & 15;        // fragment row/col index
  const int fk = lane >> 4;        // k-group 0..3

  const int lr = tid >> 3;         // staging row 0..31 (+32*p)
  const int lc = (tid & 7) * 4;    // staging k-col 0..28 within chunk

  f32x4 acc[4][4];
#pragma unroll
  for (int m = 0; m < 4; ++m)
#pragma unroll
    for (int n = 0; n < 4; ++n) {
      acc[m][n][0] = 0.f; acc[m][n][1] = 0.f;
      acc[m][n][2] = 0.f; acc[m][n][3] = 0.f;
    }

  float4 Aa[4], Ab[4], Ba[4], Bb[4];
  XLOADC(A, 0)

#pragma unroll 1
  for (int kc = 0; kc < RNN_IN; kc += 64) {
    XSTORE(A)
    { const int nk = kc + 32; XLOADC(B, nk < RNN_IN ? nk : RNN_IN - 32) }
    block_sync_lds();
    XCOMPUTE()
    block_sync_lds();
    XSTORE(B)
    { const int nk = kc + 64; XLOADC(A, nk < RNN_IN ? nk : RNN_IN - 32) }
    block_sync_lds();
    XCOMPUTE()
    block_sync_lds();
  }

  // epilogue: bias + store
  float bb[4];
#pragma unroll
  for (int n = 0; n < 4; ++n) bb[n] = bxh[wc * 64 + n * 16 + fr];
#pragma unroll
  for (int m = 0; m < 4; ++m) {
    const size_t rbase = (size_t)(m0 + wr * 64 + m * 16 + 4 * fk);
#pragma unroll
    for (int reg = 0; reg < 4; ++reg) {
      float* rowp = &xp[(rbase + reg) * RNN_H];
#pragma unroll
      for (int n = 0; n < 4; ++n)
        rowp[wc * 64 + n * 16 + fr] = acc[m][n][reg] + bb[n];
    }
  }
}

// fast tanh: 1 - 2/(exp(2x)+1); saturates correctly at +-inf
__device__ __forceinline__ float fast_tanh(float a) {
  const float e = __expf(2.f * a);
  return 1.f - 2.f / (e + 1.f);
}

// ---------------------------------------------------------------------------
// Phase 2: recurrence, ONE WAVE per batch (grid=64 blocks x 64 threads).
// Lane j owns rows 2j, 2j+1 of W_hh as 128 *named* half2 registers.
// h (128 f16 = 256 B) in LDS; each step every lane broadcast-reads all of h
// (16x ds_read_b128, uniform address = conflict-free broadcast), 128
// v_dot2_f32_f16 (fp32 acc, 8 interleaved chains), tanh, packed half2 write.
// NO s_barrier, NO explicit waitcnt in the loop: single-wave lockstep +
// in-order DS processing + compiler data-dependency waits.
// ---------------------------------------------------------------------------
union HU { float4 f4[4]; half2v h[16]; };

#define L16(M, c) \
  M(c, 0) M(c, 1) M(c, 2) M(c, 3) M(c, 4) M(c, 5) M(c, 6) M(c, 7) \
  M(c, 8) M(c, 9) M(c, 10) M(c, 11) M(c, 12) M(c, 13) M(c, 14) M(c, 15)
#define L4X16(M) L16(M, 0) L16(M, 1) L16(M, 2) L16(M, 3)

#define WDECL(c, i) half2v wA_##c##_##i; half2v wB_##c##_##i;

#define WLOAD(c, i)                                                  \
  {                                                                  \
    const float2 fa = *(const float2*)&rowA[32 * (c) + 2 * (i)];     \
    const float2 fb = *(const float2*)&rowB[32 * (c) + 2 * (i)];     \
    half2v t; t.x = (_Float16)fa.x; t.y = (_Float16)fa.y;            \
    wA_##c##_##i = t;                                                \
    half2v s; s.x = (_Float16)fb.x; s.y = (_Float16)fb.y;            \
    wB_##c##_##i = s;                                                \
  }

#define DOT(c, i)                                                    \
  accA[(i) & 3] = FDOT2(wA_##c##_##i, u##c.h[i], accA[(i) & 3]);     \
  accB[(i) & 3] = FDOT2(wB_##c##_##i, u##c.h[i], accB[(i) & 3]);

#define RNN_STEP1(PREG, TNEXT)                                       \
  {                                                                  \
    const float xin0 = PREG.x, xin1 = PREG.y;                        \
    PREG = *(const float2*)&xpb[(size_t)(TNEXT) * RNN_H];            \
    const float4* hv4 = (const float4*)hs;                           \
    HU u0, u1, u2, u3;                                               \
    u0.f4[0] = hv4[0];  u0.f4[1] = hv4[1];                           \
    u0.f4[2] = hv4[2];  u0.f4[3] = hv4[3];                           \
    u1.f4[0] = hv4[4];  u1.f4[1] = hv4[5];                           \
    u1.f4[2] = hv4[6];  u1.f4[3] = hv4[7];                           \
    u2.f4[0] = hv4[8];  u2.f4[1] = hv4[9];                           \
    u2.f4[2] = hv4[10]; u2.f4[3] = hv4[11];                          \
    u3.f4[0] = hv4[12]; u3.f4[1] = hv4[13];                          \
    u3.f4[2] = hv4[14]; u3.f4[3] = hv4[15];                          \
    float accA[4] = {0.f, 0.f, 0.f, 0.f};                            \
    float accB[4] = {0.f, 0.f, 0.f, 0.f};                            \
    L16(DOT, 0) L16(DOT, 1) L16(DOT, 2) L16(DOT, 3)                  \
    const float sA = (accA[0] + accA[1]) + (accA[2] + accA[3]);      \
    const float sB = (accB[0] + accB[1]) + (accB[2] + accB[3]);      \
    hfA = fast_tanh(biasA + xin0 + sA);                              \
    hfB = fast_tanh(biasB + xin1 + sB);                              \
    half2v hn;                                                       \
    hn.x = (_Float16)hfA;                                            \
    hn.y = (_Float16)hfB;                                            \
    *(half2v*)&hs[2 * j] = hn;                                       \
  }

__global__ __launch_bounds__(64, 1) void rnn_scan(
    const float* __restrict__ xp, const float* __restrict__ Whh,
    const float* __restrict__ bhh, const float* __restrict__ bh,
    const float* __restrict__ Wfc, const float* __restrict__ bfc,
    float* __restrict__ out) {
  const int b = blockIdx.x;
  const int j = threadIdx.x;          // lane 0..63

  __shared__ __align__(16) _Float16 hs[RNN_H];   // 256 B, single buffer
  __shared__ float fcred[RNN_OUT][64];           // FC partial reduce

  // W_hh rows 2j, 2j+1 -> 128 NAMED half2 registers (f16)
  const float* rowA = &Whh[(size_t)(2 * j) * RNN_H];
  const float* rowB = rowA + RNN_H;
  L4X16(WDECL)
  L4X16(WLOAD)

  const float biasA = bhh[2 * j] + bh[2 * j];
  const float biasB = bhh[2 * j + 1] + bh[2 * j + 1];

  // zero h (64 lanes x 4 B = 256 B); same-wave DS in-order -> no barrier
  ((float*)hs)[j] = 0.f;

  const float* xpb = xp + (size_t)b * RNN_S * RNN_H + 2 * j;

  // 4-deep prefetch of xproj pairs (float2, coalesced 512 B/wave)
  float2 p0 = *(const float2*)&xpb[0 * RNN_H];
  float2 p1 = *(const float2*)&xpb[1 * RNN_H];
  float2 p2 = *(const float2*)&xpb[2 * RNN_H];
  float2 p3 = *(const float2*)&xpb[3 * RNN_H];

  float hfA = 0.f, hfB = 0.f;

#pragma unroll 1
  for (int t = 0; t < RNN_S; t += 4) {
    const int n0 = (t + 4 < RNN_S) ? t + 4 : RNN_S - 1;
    const int n1 = (t + 5 < RNN_S) ? t + 5 : RNN_S - 1;
    const int n2 = (t + 6 < RNN_S) ? t + 6 : RNN_S - 1;
    const int n3 = (t + 7 < RNN_S) ? t + 7 : RNN_S - 1;
    RNN_STEP1(p0, n0)
    RNN_STEP1(p1, n1)
    RNN_STEP1(p2, n2)
    RNN_STEP1(p3, n3)
  }

  // fused FC using the final-step fp32 h values (hfA/hfB, un-quantized):
  // per-lane partials -> LDS -> lanes 0..2 reduce 64 values each.
#pragma unroll
  for (int o = 0; o < RNN_OUT; ++o) {
    const float2 wf = *(const float2*)&Wfc[(size_t)o * RNN_H + 2 * j];
    fcred[o][j] = wf.x * hfA + wf.y * hfB;
  }
  asm volatile("s_waitcnt lgkmcnt(0)" ::: "memory");
  if (j < RNN_OUT) {
    float s = bfc[j];
#pragma unroll 8
    for (int k = 0; k < 64; ++k) s += fcred[j][k];
    out[b * RNN_OUT + j] = s;
  }
}

extern "C" void kernel_launch(void* const* d_in, const int* in_sizes, int n_in,
                              void* d_out, int out_size, void* d_ws, size_t ws_size,
                              hipStream_t stream) {
  const float* x   = (const float*)d_in[0];
  const float* Wxh = (const float*)d_in[1];
  const float* bxh = (const float*)d_in[2];
  const float* Whh = (const float*)d_in[3];
  const float* bhh = (const float*)d_in[4];
  const float* bh  = (const float*)d_in[5];
  const float* Wfc = (const float*)d_in[6];
  const float* bfc = (const float*)d_in[7];
  float* out = (float*)d_out;
  float* xp  = (float*)d_ws;  // 131072*128*4 = 64 MiB

  xproj_mfma<<<dim3((RNN_B * RNN_S) / 128), dim3(256), 0, stream>>>(x, Wxh, bxh, xp);
  rnn_scan<<<dim3(RNN_B), dim3(64), 0, stream>>>(xp, Whh, bhh, bh, Wfc, bfc, out);
}

// Round 4
// 974.488 us; speedup vs baseline: 1.2546x; 1.2546x over previous
//
#include <hip/hip_runtime.h>
#include <hip/hip_bf16.h>
#include <hip/hip_fp16.h>

// SimpleRNN: B=64, S=2048, IN=256, H=128, OUT=3 (all fp32)
// Phase 1: xproj MFMA GEMM (byte-identical to r12; residual ~205 us is
//   mostly fixed overhead -- three different implementations all ~205).
// Phase 2 (r13): 2 waves/batch, ONE W_hh row per lane = 64 half2 VGPRs
//   (r11/r12 needed 128/lane -> allocator refused ~190 regs, spilled at
//   92-96 VGPR). 64 regs + asm "+v" pinning makes residency certain:
//   the asm is the def, so loads can't be sunk/remat'd into the loop.
//   h f16 double-buffered in LDS, broadcast ds_read_b128 (uniform addr,
//   conflict-free), no cross-lane reduce, 1 two-wave barrier/step.

#define RNN_B   64
#define RNN_S   2048
#define RNN_IN  256
#define RNN_H   128
#define RNN_OUT 3

typedef _Float16 half2v __attribute__((ext_vector_type(2)));
typedef _Float16 half4 __attribute__((ext_vector_type(4)));
typedef _Float16 half8 __attribute__((ext_vector_type(8)));
typedef float f32x4 __attribute__((ext_vector_type(4)));

#if __has_builtin(__builtin_amdgcn_fdot2)
#define FDOT2(a, b, c) __builtin_amdgcn_fdot2((a), (b), (c), false)
#else
#define FDOT2(a, b, c) \
  fmaf((float)(a).x, (float)(b).x, fmaf((float)(a).y, (float)(b).y, (c)))
#endif

// LDS-only barrier: drains lgkm (LDS) but NOT vmcnt, so global prefetch
// loads stay in flight across the barrier.
__device__ __forceinline__ void block_sync_lds() {
  asm volatile("s_waitcnt lgkmcnt(0)" ::: "memory");
  __builtin_amdgcn_s_barrier();
}

// ---------------------------------------------------------------------------
// Phase 1: f16 MFMA GEMM  C[M=131072, N=128] = A[M,256] * B[128,256]^T + bias
// (byte-identical to round 3 for attribution)
// ---------------------------------------------------------------------------
#define XLOADC(SET, KC)                                                       \
  {                                                                           \
    const int _kc = (KC);                                                     \
    _Pragma("unroll")                                                         \
    for (int p = 0; p < 4; ++p) {                                             \
      const int row = lr + 32 * p;                                            \
      SET##a[p] = *(const float4*)&x[(size_t)(m0 + row) * RNN_IN + _kc + lc]; \
      SET##b[p] = *(const float4*)&Wxh[(size_t)row * RNN_IN + _kc + lc];      \
    }                                                                         \
  }

#define XSTORE(SET)                                                 \
  {                                                                 \
    _Pragma("unroll")                                               \
    for (int p = 0; p < 4; ++p) {                                   \
      const int row = lr + 32 * p;                                  \
      half4 ha, hb;                                                 \
      ha.x = (_Float16)SET##a[p].x; ha.y = (_Float16)SET##a[p].y;   \
      ha.z = (_Float16)SET##a[p].z; ha.w = (_Float16)SET##a[p].w;   \
      hb.x = (_Float16)SET##b[p].x; hb.y = (_Float16)SET##b[p].y;   \
      hb.z = (_Float16)SET##b[p].z; hb.w = (_Float16)SET##b[p].w;   \
      *(half4*)&Ash[row][lc] = ha;                                  \
      *(half4*)&Bsh[row][lc] = hb;                                  \
    }                                                               \
  }

#define XCOMPUTE()                                                  \
  {                                                                 \
    half8 af[4], bf[4];                                             \
    _Pragma("unroll")                                               \
    for (int m = 0; m < 4; ++m)                                     \
      af[m] = *(const half8*)&Ash[wr * 64 + m * 16 + fr][fk * 8];   \
    _Pragma("unroll")                                               \
    for (int n = 0; n < 4; ++n)                                     \
      bf[n] = *(const half8*)&Bsh[wc * 64 + n * 16 + fr][fk * 8];   \
    _Pragma("unroll")                                               \
    for (int m = 0; m < 4; ++m)                                     \
      _Pragma("unroll")                                             \
      for (int n = 0; n < 4; ++n)                                   \
        acc[m][n] = __builtin_amdgcn_mfma_f32_16x16x32_f16(         \
            af[m], bf[n], acc[m][n], 0, 0, 0);                      \
  }

__global__ __launch_bounds__(256, 2) void xproj_mfma(
    const float* __restrict__ x, const float* __restrict__ Wxh,
    const float* __restrict__ bxh, float* __restrict__ xp) {
  __shared__ __align__(16) _Float16 Ash[128][40];
  __shared__ __align__(16) _Float16 Bsh[128][40];

  const int tid = threadIdx.x;
  const int m0 = blockIdx.x * 128;
  const int wv = tid >> 6;
  const int lane = tid & 63;
  const int wr = wv >> 1;
  const int wc = wv & 1;
  const int fr = lane & 15;
  const int fk = lane >> 4;

  const int lr = tid >> 3;
  const int lc = (tid & 7) * 4;

  f32x4 acc[4][4];
#pragma unroll
  for (int m = 0; m < 4; ++m)
#pragma unroll
    for (int n = 0; n < 4; ++n) {
      acc[m][n][0] = 0.f; acc[m][n][1] = 0.f;
      acc[m][n][2] = 0.f; acc[m][n][3] = 0.f;
    }

  float4 Aa[4], Ab[4], Ba[4], Bb[4];
  XLOADC(A, 0)

#pragma unroll 1
  for (int kc = 0; kc < RNN_IN; kc += 64) {
    XSTORE(A)
    { const int nk = kc + 32; XLOADC(B, nk < RNN_IN ? nk : RNN_IN - 32) }
    block_sync_lds();
    XCOMPUTE()
    block_sync_lds();
    XSTORE(B)
    { const int nk = kc + 64; XLOADC(A, nk < RNN_IN ? nk : RNN_IN - 32) }
    block_sync_lds();
    XCOMPUTE()
    block_sync_lds();
  }

  float bb[4];
#pragma unroll
  for (int n = 0; n < 4; ++n) bb[n] = bxh[wc * 64 + n * 16 + fr];
#pragma unroll
  for (int m = 0; m < 4; ++m) {
    const size_t rbase = (size_t)(m0 + wr * 64 + m * 16 + 4 * fk);
#pragma unroll
    for (int reg = 0; reg < 4; ++reg) {
      float* rowp = &xp[(rbase + reg) * RNN_H];
#pragma unroll
      for (int n = 0; n < 4; ++n)
        rowp[wc * 64 + n * 16 + fr] = acc[m][n][reg] + bb[n];
    }
  }
}

// fast tanh: 1 - 2/(exp(2x)+1); saturates correctly at +-inf
__device__ __forceinline__ float fast_tanh(float a) {
  const float e = __expf(2.f * a);
  return 1.f - 2.f / (e + 1.f);
}

// ---------------------------------------------------------------------------
// Phase 2: recurrence. grid=64 (one per batch), block=128 (2 waves).
// Lane r = tid owns W_hh row r as 64 NAMED+PINNED half2 VGPRs.
// ---------------------------------------------------------------------------

// weight regs w0..w63
#define WDECL(i) half2v w##i;
#define W_ALL(M) \
  M(0)  M(1)  M(2)  M(3)  M(4)  M(5)  M(6)  M(7)  \
  M(8)  M(9)  M(10) M(11) M(12) M(13) M(14) M(15) \
  M(16) M(17) M(18) M(19) M(20) M(21) M(22) M(23) \
  M(24) M(25) M(26) M(27) M(28) M(29) M(30) M(31) \
  M(32) M(33) M(34) M(35) M(36) M(37) M(38) M(39) \
  M(40) M(41) M(42) M(43) M(44) M(45) M(46) M(47) \
  M(48) M(49) M(50) M(51) M(52) M(53) M(54) M(55) \
  M(56) M(57) M(58) M(59) M(60) M(61) M(62) M(63)

// load one float4 (idx) -> two half2 regs (i0 = 2*idx, i1 = 2*idx+1)
#define WLOAD2(i0, i1, idx)                                   \
  {                                                           \
    const float4 f = rowp4[idx];                              \
    half2v t; t.x = (_Float16)f.x; t.y = (_Float16)f.y;       \
    w##i0 = t;                                                \
    half2v s; s.x = (_Float16)f.z; s.y = (_Float16)f.w;       \
    w##i1 = s;                                                \
  }
#define W_PAIRS(M) \
  M(0,1,0)   M(2,3,1)   M(4,5,2)   M(6,7,3)   \
  M(8,9,4)   M(10,11,5) M(12,13,6) M(14,15,7) \
  M(16,17,8) M(18,19,9) M(20,21,10) M(22,23,11) \
  M(24,25,12) M(26,27,13) M(28,29,14) M(30,31,15) \
  M(32,33,16) M(34,35,17) M(36,37,18) M(38,39,19) \
  M(40,41,20) M(42,43,21) M(44,45,22) M(46,47,23) \
  M(48,49,24) M(50,51,25) M(52,53,26) M(54,55,27) \
  M(56,57,28) M(58,59,29) M(60,61,30) M(62,63,31)

// one 16-B h-chunk: 4 dot2 against weight regs wa..wd, 4 indep acc chains
#define DOT4(c, wa, wb, wc_, wd)                                      \
  {                                                                   \
    const float4 v = hb4[c];                                          \
    a0 = FDOT2(wa,  __builtin_bit_cast(half2v, v.x), a0);             \
    a1 = FDOT2(wb,  __builtin_bit_cast(half2v, v.y), a1);             \
    a2 = FDOT2(wc_, __builtin_bit_cast(half2v, v.z), a2);             \
    a3 = FDOT2(wd,  __builtin_bit_cast(half2v, v.w), a3);             \
  }

#define RNN_STEP1(PREG, TNEXT, CUR, NXT)                              \
  {                                                                   \
    const float xin = PREG;                                           \
    PREG = xpb[(size_t)(TNEXT) * RNN_H];                              \
    const float4* hb4 = (const float4*)hbuf[CUR];                     \
    float a0 = 0.f, a1 = 0.f, a2 = 0.f, a3 = 0.f;                     \
    DOT4(0,  w0,  w1,  w2,  w3)                                       \
    DOT4(1,  w4,  w5,  w6,  w7)                                       \
    DOT4(2,  w8,  w9,  w10, w11)                                      \
    DOT4(3,  w12, w13, w14, w15)                                      \
    DOT4(4,  w16, w17, w18, w19)                                      \
    DOT4(5,  w20, w21, w22, w23)                                      \
    DOT4(6,  w24, w25, w26, w27)                                      \
    DOT4(7,  w28, w29, w30, w31)                                      \
    DOT4(8,  w32, w33, w34, w35)                                      \
    DOT4(9,  w36, w37, w38, w39)                                      \
    DOT4(10, w40, w41, w42, w43)                                      \
    DOT4(11, w44, w45, w46, w47)                                      \
    DOT4(12, w48, w49, w50, w51)                                      \
    DOT4(13, w52, w53, w54, w55)                                      \
    DOT4(14, w56, w57, w58, w59)                                      \
    DOT4(15, w60, w61, w62, w63)                                      \
    const float s = (a0 + a1) + (a2 + a3);                            \
    hfF = fast_tanh(bias + xin + s);                                  \
    hbuf[NXT][r] = (_Float16)hfF;                                     \
    block_sync_lds();                                                 \
  }

__global__ __launch_bounds__(128, 1) void rnn_scan(
    const float* __restrict__ xp, const float* __restrict__ Whh,
    const float* __restrict__ bhh, const float* __restrict__ bh,
    const float* __restrict__ Wfc, const float* __restrict__ bfc,
    float* __restrict__ out) {
  const int b = blockIdx.x;
  const int r = threadIdx.x;          // row 0..127

  __shared__ __align__(16) _Float16 hbuf[2][RNN_H];  // 512 B double buffer
  __shared__ float fcred[RNN_OUT][RNN_H];            // FC partial reduce

  const float4* rowp4 = (const float4*)&Whh[(size_t)r * RNN_H];
  W_ALL(WDECL)
  W_PAIRS(WLOAD2)

  // Pin the 64 weight regs: the asm is now their def -- the compiler can
  // neither sink the global loads into the loop nor scratch them silently.
  asm volatile("" : "+v"(w0), "+v"(w1), "+v"(w2), "+v"(w3),
                    "+v"(w4), "+v"(w5), "+v"(w6), "+v"(w7),
                    "+v"(w8), "+v"(w9), "+v"(w10), "+v"(w11),
                    "+v"(w12), "+v"(w13), "+v"(w14), "+v"(w15));
  asm volatile("" : "+v"(w16), "+v"(w17), "+v"(w18), "+v"(w19),
                    "+v"(w20), "+v"(w21), "+v"(w22), "+v"(w23),
                    "+v"(w24), "+v"(w25), "+v"(w26), "+v"(w27),
                    "+v"(w28), "+v"(w29), "+v"(w30), "+v"(w31));
  asm volatile("" : "+v"(w32), "+v"(w33), "+v"(w34), "+v"(w35),
                    "+v"(w36), "+v"(w37), "+v"(w38), "+v"(w39),
                    "+v"(w40), "+v"(w41), "+v"(w42), "+v"(w43),
                    "+v"(w44), "+v"(w45), "+v"(w46), "+v"(w47));
  asm volatile("" : "+v"(w48), "+v"(w49), "+v"(w50), "+v"(w51),
                    "+v"(w52), "+v"(w53), "+v"(w54), "+v"(w55),
                    "+v"(w56), "+v"(w57), "+v"(w58), "+v"(w59),
                    "+v"(w60), "+v"(w61), "+v"(w62), "+v"(w63));

  const float bias = bhh[r] + bh[r];

  // zero h buffer 0
  hbuf[0][r] = (_Float16)0.f;
  block_sync_lds();

  const float* xpb = xp + (size_t)b * RNN_S * RNN_H + r;

  // 4-deep fp32 prefetch (coalesced 512 B per 128 threads)
  float p0 = xpb[0 * RNN_H];
  float p1 = xpb[1 * RNN_H];
  float p2 = xpb[2 * RNN_H];
  float p3 = xpb[3 * RNN_H];

  float hfF = 0.f;

#pragma unroll 1
  for (int t = 0; t < RNN_S; t += 4) {
    const int n0 = (t + 4 < RNN_S) ? t + 4 : RNN_S - 1;
    const int n1 = (t + 5 < RNN_S) ? t + 5 : RNN_S - 1;
    const int n2 = (t + 6 < RNN_S) ? t + 6 : RNN_S - 1;
    const int n3 = (t + 7 < RNN_S) ? t + 7 : RNN_S - 1;
    RNN_STEP1(p0, n0, 0, 1)
    RNN_STEP1(p1, n1, 1, 0)
    RNN_STEP1(p2, n2, 0, 1)
    RNN_STEP1(p3, n3, 1, 0)
  }
  // final h (fp32, un-quantized) is in hfF for row r.

  // fused FC: per-lane partials -> LDS -> lanes 0..2 reduce 128 each.
#pragma unroll
  for (int o = 0; o < RNN_OUT; ++o)
    fcred[o][r] = Wfc[(size_t)o * RNN_H + r] * hfF;
  block_sync_lds();
  if (r < RNN_OUT) {
    float s = bfc[r];
#pragma unroll 8
    for (int k = 0; k < RNN_H; ++k) s += fcred[r][k];
    out[b * RNN_OUT + r] = s;
  }
}

extern "C" void kernel_launch(void* const* d_in, const int* in_sizes, int n_in,
                              void* d_out, int out_size, void* d_ws, size_t ws_size,
                              hipStream_t stream) {
  const float* x   = (const float*)d_in[0];
  const float* Wxh = (const float*)d_in[1];
  const float* bxh = (const float*)d_in[2];
  const float* Whh = (const float*)d_in[3];
  const float* bhh = (const float*)d_in[4];
  const float* bh  = (const float*)d_in[5];
  const float* Wfc = (const float*)d_in[6];
  const float* bfc = (const float*)d_in[7];
  float* out = (float*)d_out;
  float* xp  = (float*)d_ws;  // 131072*128*4 = 64 MiB

  xproj_mfma<<<dim3((RNN_B * RNN_S) / 128), dim3(256), 0, stream>>>(x, Wxh, bxh, xp);
  rnn_scan<<<dim3(RNN_B), dim3(128), 0, stream>>>(xp, Whh, bhh, bh, Wfc, bfc, out);
}